// Round 10
// baseline (82.401 us; speedup 1.0000x reference)
//
#include <hip/hip_runtime.h>
#include <hip/hip_fp16.h>

#define DEV static __device__ __forceinline__

constexpr int NTOK = 8 * 2048;       // B*T
constexpr float LN_EPS = 1e-5f;

using half4  = __attribute__((ext_vector_type(4))) _Float16;
using half8  = __attribute__((ext_vector_type(8))) _Float16;
using f32x4  = __attribute__((ext_vector_type(4))) float;
using f32x16 = __attribute__((ext_vector_type(16))) float;

DEV __half2 bch2(unsigned u) { return __builtin_bit_cast(__half2, u); }
DEV unsigned bcu(__half2 h)  { return __builtin_bit_cast(unsigned, h); }

#define MFMA16(a, b, c)    __builtin_amdgcn_mfma_f32_16x16x16f16(a, b, c, 0, 0, 0)
#define MFMA32(a, b, c)    __builtin_amdgcn_mfma_f32_32x32x8f16(a, b, c, 0, 0, 0)
#define MFMA32X16(a, b, c) __builtin_amdgcn_mfma_f32_32x32x16_f16(a, b, c, 0, 0, 0)

DEV half4 pk4(float a, float b, float c, float d) {
  unsigned lo = __builtin_bit_cast(unsigned, __builtin_amdgcn_cvt_pkrtz(a, b));
  unsigned hi = __builtin_bit_cast(unsigned, __builtin_amdgcn_cvt_pkrtz(c, d));
  uint2 u = make_uint2(lo, hi);
  return __builtin_bit_cast(half4, u);
}
DEV half8 cat8(uint2 a, uint2 b) {
  uint4 u = make_uint4(a.x, a.y, b.x, b.y);
  return __builtin_bit_cast(half8, u);
}
DEV half8 cat8h(half4 a, half4 b) {
  return cat8(__builtin_bit_cast(uint2, a), __builtin_bit_cast(uint2, b));
}

// Schraudolph exp2: one v_fma_f32 + one v_cvt_i32_f32. Rel err [-2.2%,+3.0%];
// softmax denom uses the SAME approximated P (ones-row MFMA) -> common-mode.
DEV float schr(float x) {
  return __builtin_bit_cast(float, (int)__builtin_fmaf(x, 8388608.0f, 1064987473.0f));
}

// ------------------------------ K1: LN1 + QKV via MFMA transposed chain
// Writes Q,K in [bh][t][8] f16; V TRANSPOSED to VT[bh][9][2048] f16 (plane-
// major) for K2's LDS-free A-fragment reads. Also prefills VT row 8 = ones
// (softmax-denominator row).
__global__ __launch_bounds__(256) void k_ln_qkv(
    const float* __restrict__ x, const float* __restrict__ Wq,
    const float* __restrict__ Wk, const float* __restrict__ Wv,
    const float* __restrict__ g1, const float* __restrict__ b1g,
    __half* __restrict__ Qo, __half* __restrict__ Ko, __half* __restrict__ VTg)
{
  __shared__ __align__(16) __half WqF[4096];   // 8KB [mt4|kt4][lane][j]
  __shared__ __align__(16) __half WkF[4096];
  __shared__ __align__(16) __half WvF[4096];
  const int tid = threadIdx.x, lane = tid & 63, wid = tid >> 6;
  const int l15 = lane & 15, gg = lane >> 4;
  const float qs = 0.35355339059327373f * 1.4426950408889634f;  // hs^-0.5 * log2e

  // ---- ones plane: block bid covers bh=bid/4, quarter bid%4 (256 thr * 1 dword)
  {
    int bh_ = blockIdx.x >> 2, qq = blockIdx.x & 3;
    unsigned* onep = (unsigned*)(VTg + ((bh_ * 9 + 8) * 2048) + qq * 512);
    onep[tid] = 0x3C003C00u;
  }

  for (int idx = tid; idx < 1024; idx += 256) {
    int mt = idx >> 8, kt = (idx >> 6) & 3, l = idx & 63;
    int row = l & 15, g = l >> 4;
    int off = (mt * 16 + row) * 64 + kt * 16 + g * 4;
    float4 a = *(const float4*)(Wq + off);
    float4 b = *(const float4*)(Wk + off);
    float4 c = *(const float4*)(Wv + off);
    half4 hq; hq[0] = (_Float16)(a.x*qs); hq[1] = (_Float16)(a.y*qs);
    hq[2] = (_Float16)(a.z*qs); hq[3] = (_Float16)(a.w*qs);
    half4 hk; hk[0] = (_Float16)b.x; hk[1] = (_Float16)b.y;
    hk[2] = (_Float16)b.z; hk[3] = (_Float16)b.w;
    half4 hv; hv[0] = (_Float16)c.x; hv[1] = (_Float16)c.y;
    hv[2] = (_Float16)c.z; hv[3] = (_Float16)c.w;
    *(half4*)&WqF[idx * 4] = hq;
    *(half4*)&WkF[idx * 4] = hk;
    *(half4*)&WvF[idx * 4] = hv;
  }
  __syncthreads();

  const int tok = (blockIdx.x * 4 + wid) * 16 + l15;
  const int b = tok >> 11, t = tok & 2047;
  float4 xv[4];
  float sum = 0.f, sq = 0.f;
  #pragma unroll
  for (int kt = 0; kt < 4; ++kt) {
    xv[kt] = *(const float4*)(x + tok * 64 + kt * 16 + gg * 4);
    sum += xv[kt].x + xv[kt].y + xv[kt].z + xv[kt].w;
    sq  += xv[kt].x*xv[kt].x + xv[kt].y*xv[kt].y
         + xv[kt].z*xv[kt].z + xv[kt].w*xv[kt].w;
  }
  sum += __shfl_xor(sum, 16); sum += __shfl_xor(sum, 32);
  sq  += __shfl_xor(sq, 16);  sq  += __shfl_xor(sq, 32);
  float mu = sum * (1.0f / 64.0f);
  float var = sq * (1.0f / 64.0f) - mu * mu;
  float rs = rsqrtf(var + LN_EPS);
  half4 hb[4];
  #pragma unroll
  for (int kt = 0; kt < 4; ++kt) {
    float4 gv = *(const float4*)(g1 + kt * 16 + gg * 4);
    float4 bv = *(const float4*)(b1g + kt * 16 + gg * 4);
    hb[kt][0] = (_Float16)((xv[kt].x - mu) * rs * gv.x + bv.x);
    hb[kt][1] = (_Float16)((xv[kt].y - mu) * rs * gv.y + bv.y);
    hb[kt][2] = (_Float16)((xv[kt].z - mu) * rs * gv.z + bv.z);
    hb[kt][3] = (_Float16)((xv[kt].w - mu) * rs * gv.w + bv.w);
  }
  #pragma unroll
  for (int mt = 0; mt < 4; ++mt) {
    f32x4 oq = {}, ok = {}, ov = {};
    #pragma unroll
    for (int kt = 0; kt < 4; ++kt) {
      half4 q_a = *(const half4*)&WqF[((mt * 4 + kt) * 64 + lane) * 4];
      half4 k_a = *(const half4*)&WkF[((mt * 4 + kt) * 64 + lane) * 4];
      half4 v_a = *(const half4*)&WvF[((mt * 4 + kt) * 64 + lane) * 4];
      oq = MFMA16(q_a, hb[kt], oq);
      ok = MFMA16(k_a, hb[kt], ok);
      ov = MFMA16(v_a, hb[kt], ov);
    }
    const int sg = mt * 16 + gg * 4;         // global output feature (h*8+s)
    const int h = sg >> 3, sq0 = sg & 7;     // sq0 in {0,4}; j-quad stays in one h
    const long qbase = ((long)(b * 8 + h) * 2048 + t) * 8 + sq0;
    *(half4*)(Qo + qbase) = pk4(oq[0], oq[1], oq[2], oq[3]);
    *(half4*)(Ko + qbase) = pk4(ok[0], ok[1], ok[2], ok[3]);
    // V transposed: VT[(b*8+h)*9 + sq0+j][t]
    __half* vtp = VTg + ((long)((b * 8 + h) * 9 + sq0) * 2048) + t;
    vtp[0]    = __float2half(ov[0]);
    vtp[2048] = __float2half(ov[1]);
    vtp[4096] = __float2half(ov[2]);
    vtp[6144] = __float2half(ov[3]);
  }
}

// ---------------------------------------------------------------- K2: MFMA attention
// LDS-FREE. grid (64 bh, 16 q-blocks of 128), 4 waves/block, wave owns 32 q.
// S^T = K·Q^T via 32x32x8 (K=8=hs); PV via 32x32x16: S C-regs ARE the PV
// B-fragment (e0..7 | e8..15), zero cross-lane moves. V^T A-frags read
// straight from global VT[bh][9][2048] (L2-resident, ~75MB total ≈ 2µs).
// Row 8 = ones -> denom = O^T row 8 (reg 4); lanes d>8 clamp to ones row
// (pollutes only unread C rows). Dual accumulators (oe/oo) break the MFMA
// accumulation chain; 2-stage software pipeline prefetches K+V one body ahead.
// No barriers, no LDS -> occupancy VGPR-bound: launch_bounds(256,4) = 4 w/SIMD.
__global__ __launch_bounds__(256, 4) void k_attn(
    const __half* __restrict__ Qg, const __half* __restrict__ Kg,
    const __half* __restrict__ VTg, __half* __restrict__ Og)
{
  const int tid = threadIdx.x, lane = tid & 63, wid = tid >> 6;
  const int bh = blockIdx.x;
  const int base = bh << 14;                  // *2048*8 elements
  const int b = bh >> 3, hh = bh & 7;
  const int l31 = lane & 31, hi = lane >> 5;
  const int q0 = blockIdx.y * 128 + wid * 32;
  // Q^T B-frag (col=q=l31, k=hi*4+j)
  half4 qf = *(const half4*)((const char*)(Qg + base) + (q0 + l31) * 16 + hi * 8);
  // K A-frag stream: row=key=l31, k=hi*4+j; +c*512B per 32-key body
  const char* kp = (const char*)(Kg + base) + l31 * 16 + hi * 8;
  // V^T A-frag stream: row=d=l31 (clamp >=8 -> ones row), +c*64B per body
  const int deff = (l31 <= 8) ? l31 : 8;
  const char* vt = (const char*)(VTg + ((bh * 9 + deff) << 11)) + hi * 8;

  const f32x16 z = {};
  f32x16 oe = {}, oo = {};

  half4 kfA = *(const half4*)(kp);
  uint2 aA0 = *(const uint2*)(vt);
  uint2 aA1 = *(const uint2*)(vt + 16);
  uint2 aA2 = *(const uint2*)(vt + 32);
  uint2 aA3 = *(const uint2*)(vt + 48);

  #pragma unroll 4
  for (int c = 0; c < 64; c += 2) {
    // prefetch body c+1
    half4 kfB = *(const half4*)(kp + (c + 1) * 512);
    uint2 bB0 = *(const uint2*)(vt + (c + 1) * 64);
    uint2 bB1 = *(const uint2*)(vt + (c + 1) * 64 + 16);
    uint2 bB2 = *(const uint2*)(vt + (c + 1) * 64 + 32);
    uint2 bB3 = *(const uint2*)(vt + (c + 1) * 64 + 48);
    // compute body c -> oe
    {
      f32x16 s0 = MFMA32(kfA, qf, z);
      half4 p0 = pk4(schr(s0[0]),  schr(s0[1]),  schr(s0[2]),  schr(s0[3]));
      half4 p1 = pk4(schr(s0[4]),  schr(s0[5]),  schr(s0[6]),  schr(s0[7]));
      oe = MFMA32X16(cat8(aA0, aA1), cat8h(p0, p1), oe);
      half4 p2 = pk4(schr(s0[8]),  schr(s0[9]),  schr(s0[10]), schr(s0[11]));
      half4 p3 = pk4(schr(s0[12]), schr(s0[13]), schr(s0[14]), schr(s0[15]));
      oe = MFMA32X16(cat8(aA2, aA3), cat8h(p2, p3), oe);
    }
    // prefetch body c+2
    if (c < 62) {
      kfA = *(const half4*)(kp + (c + 2) * 512);
      aA0 = *(const uint2*)(vt + (c + 2) * 64);
      aA1 = *(const uint2*)(vt + (c + 2) * 64 + 16);
      aA2 = *(const uint2*)(vt + (c + 2) * 64 + 32);
      aA3 = *(const uint2*)(vt + (c + 2) * 64 + 48);
    }
    // compute body c+1 -> oo
    {
      f32x16 s1 = MFMA32(kfB, qf, z);
      half4 p0 = pk4(schr(s1[0]),  schr(s1[1]),  schr(s1[2]),  schr(s1[3]));
      half4 p1 = pk4(schr(s1[4]),  schr(s1[5]),  schr(s1[6]),  schr(s1[7]));
      oo = MFMA32X16(cat8(bB0, bB1), cat8h(p0, p1), oo);
      half4 p2 = pk4(schr(s1[8]),  schr(s1[9]),  schr(s1[10]), schr(s1[11]));
      half4 p3 = pk4(schr(s1[12]), schr(s1[13]), schr(s1[14]), schr(s1[15]));
      oo = MFMA32X16(cat8(bB2, bB3), cat8h(p2, p3), oo);
    }
  }

  // ---- epilogue: l = O^T row 8 (reg 4, lo half); out rows r+4*hi
  float l0 = __shfl(oe[4] + oo[4], l31);
  float inv = 1.0f / l0;
  half4 r;
  r[0] = (_Float16)((oe[0] + oo[0]) * inv);
  r[1] = (_Float16)((oe[1] + oo[1]) * inv);
  r[2] = (_Float16)((oe[2] + oo[2]) * inv);
  r[3] = (_Float16)((oe[3] + oo[3]) * inv);
  *(half4*)(Og + ((b * 2048 + q0 + l31) * 64) + hh * 8 + hi * 4) = r;
}

// ------------------------- K3: MFMA proj + res + LN2 + MLP + res (transposed chain)
__global__ __launch_bounds__(256) void k_proj_mlp(
    const float* __restrict__ x, const __half* __restrict__ Og,
    const float* __restrict__ Wproj, const float* __restrict__ bproj,
    const float* __restrict__ W1, const float* __restrict__ b1,
    const float* __restrict__ W2, const float* __restrict__ b2,
    const float* __restrict__ g2, const float* __restrict__ bb2,
    float* __restrict__ out)
{
  __shared__ __align__(16) __half WpF[4096];    // 8KB  [mt4|kt4][lane][j]
  __shared__ __align__(16) __half W1F[16384];   // 32KB [mt16|kt4][lane][j]
  __shared__ __align__(16) __half W2F[16384];   // 32KB [mt4|kt16][lane][j]
  __shared__ __align__(16) float biasLDS[512];  // bproj@0 g2@64 bb2@128 b2@192 b1@256
  const int tid = threadIdx.x, lane = tid & 63, wid = tid >> 6;
  const int l15 = lane & 15, gg = lane >> 4;

  for (int idx = tid; idx < 1024; idx += 256) {
    int mt = idx >> 8, kt = (idx >> 6) & 3, l = idx & 63;
    int row = l & 15, g = l >> 4;
    float4 w = *(const float4*)(Wproj + (mt * 16 + row) * 64 + kt * 16 + g * 4);
    half4 h; h[0] = (_Float16)w.x; h[1] = (_Float16)w.y;
    h[2] = (_Float16)w.z; h[3] = (_Float16)w.w;
    *(half4*)&WpF[idx * 4] = h;
  }
  for (int idx = tid; idx < 4096; idx += 256) {
    int mt2 = idx >> 8, kt = (idx >> 6) & 3, l = idx & 63;
    int row = l & 15, g = l >> 4;
    float4 w = *(const float4*)(W1 + (mt2 * 16 + row) * 64 + kt * 16 + g * 4);
    half4 h; h[0] = (_Float16)w.x; h[1] = (_Float16)w.y;
    h[2] = (_Float16)w.z; h[3] = (_Float16)w.w;
    *(half4*)&W1F[idx * 4] = h;
  }
  for (int idx = tid; idx < 4096; idx += 256) {
    int mt = idx >> 10, kt2 = (idx >> 6) & 15, l = idx & 63;
    int row = l & 15, g = l >> 4;
    float4 w = *(const float4*)(W2 + (mt * 16 + row) * 256 + kt2 * 16 + g * 4);
    half4 h; h[0] = (_Float16)w.x; h[1] = (_Float16)w.y;
    h[2] = (_Float16)w.z; h[3] = (_Float16)w.w;
    *(half4*)&W2F[idx * 4] = h;
  }
  for (int idx = tid; idx < 512; idx += 256) {
    float v;
    if      (idx <  64) v = bproj[idx];
    else if (idx < 128) v = g2[idx - 64];
    else if (idx < 192) v = bb2[idx - 128];
    else if (idx < 256) v = b2[idx - 192];
    else                v = b1[idx - 256];
    biasLDS[idx] = v;
  }
  __syncthreads();

  const int tile = blockIdx.x * 4 + wid;
  const int tok = tile * 16 + l15;

  const __half* orow = Og + tok * 64;
  half4 ob[4];
  #pragma unroll
  for (int kt = 0; kt < 4; ++kt)
    ob[kt] = __builtin_bit_cast(half4, *(const uint2*)(orow + kt * 16 + gg * 4));

  f32x4 acc[4];
  #pragma unroll
  for (int mt = 0; mt < 4; ++mt) {
    float4 xv = *(const float4*)(x + tok * 64 + mt * 16 + gg * 4);
    float4 bp = *(const float4*)&biasLDS[mt * 16 + gg * 4];
    acc[mt] = (f32x4){xv.x + bp.x, xv.y + bp.y, xv.z + bp.z, xv.w + bp.w};
    #pragma unroll
    for (int kt = 0; kt < 4; ++kt) {
      half4 wa = *(const half4*)&WpF[((mt * 4 + kt) * 64 + lane) * 4];
      acc[mt] = MFMA16(wa, ob[kt], acc[mt]);
    }
  }
  float sum = 0.f, sq = 0.f;
  #pragma unroll
  for (int mt = 0; mt < 4; ++mt) {
    #pragma unroll
    for (int r = 0; r < 4; ++r) { float v = acc[mt][r]; sum += v; sq += v * v; }
  }
  sum += __shfl_xor(sum, 16); sum += __shfl_xor(sum, 32);
  sq  += __shfl_xor(sq, 16);  sq  += __shfl_xor(sq, 32);
  float mu = sum * (1.0f / 64.0f);
  float var = sq * (1.0f / 64.0f) - mu * mu;
  float rs = rsqrtf(var + LN_EPS);
  half4 hb[4];
  #pragma unroll
  for (int mt = 0; mt < 4; ++mt) {
    float4 gv = *(const float4*)&biasLDS[64 + mt * 16 + gg * 4];
    float4 bv = *(const float4*)&biasLDS[128 + mt * 16 + gg * 4];
    hb[mt][0] = (_Float16)((acc[mt][0] - mu) * rs * gv.x + bv.x);
    hb[mt][1] = (_Float16)((acc[mt][1] - mu) * rs * gv.y + bv.y);
    hb[mt][2] = (_Float16)((acc[mt][2] - mu) * rs * gv.z + bv.z);
    hb[mt][3] = (_Float16)((acc[mt][3] - mu) * rs * gv.w + bv.w);
  }
  half4 pf[16];
  #pragma unroll
  for (int mt2 = 0; mt2 < 16; ++mt2) {
    float4 b1v = *(const float4*)&biasLDS[256 + mt2 * 16 + gg * 4];
    f32x4 f = (f32x4){b1v.x, b1v.y, b1v.z, b1v.w};
    #pragma unroll
    for (int kt = 0; kt < 4; ++kt) {
      half4 wa = *(const half4*)&W1F[((mt2 * 4 + kt) * 64 + lane) * 4];
      f = MFMA16(wa, hb[kt], f);
    }
    pf[mt2][0] = (_Float16)fmaxf(f[0], 0.f);
    pf[mt2][1] = (_Float16)fmaxf(f[1], 0.f);
    pf[mt2][2] = (_Float16)fmaxf(f[2], 0.f);
    pf[mt2][3] = (_Float16)fmaxf(f[3], 0.f);
  }
  #pragma unroll
  for (int mt = 0; mt < 4; ++mt) {
    float4 b2v = *(const float4*)&biasLDS[192 + mt * 16 + gg * 4];
    f32x4 o = (f32x4){acc[mt][0] + b2v.x, acc[mt][1] + b2v.y,
                      acc[mt][2] + b2v.z, acc[mt][3] + b2v.w};
    #pragma unroll
    for (int kt2 = 0; kt2 < 16; ++kt2) {
      half4 wa = *(const half4*)&W2F[((mt * 16 + kt2) * 64 + lane) * 4];
      o = MFMA16(wa, pf[kt2], o);
    }
    *(float4*)(out + tok * 64 + mt * 16 + gg * 4) =
        make_float4(o[0], o[1], o[2], o[3]);
  }
}

// ---------------------------------------------------------------- launch
extern "C" void kernel_launch(void* const* d_in, const int* in_sizes, int n_in,
                              void* d_out, int out_size, void* d_ws, size_t ws_size,
                              hipStream_t stream) {
  const float* x     = (const float*)d_in[0];
  const float* Wq    = (const float*)d_in[1];
  const float* Wk    = (const float*)d_in[2];
  const float* Wv    = (const float*)d_in[3];
  const float* Wproj = (const float*)d_in[4];
  const float* bproj = (const float*)d_in[5];
  const float* W1    = (const float*)d_in[6];
  const float* b1    = (const float*)d_in[7];
  const float* W2    = (const float*)d_in[8];
  const float* b2    = (const float*)d_in[9];
  const float* g1    = (const float*)d_in[10];
  const float* bb1   = (const float*)d_in[11];
  const float* g2    = (const float*)d_in[12];
  const float* bb2   = (const float*)d_in[13];
  float* out = (float*)d_out;

  __half* Qh = (__half*)d_ws;            // [64][2048][8] f16 : 2MB
  __half* Kh = Qh + 1048576;             // 2MB
  __half* VT = Kh + 1048576;             // [64][9][2048] f16 : 2.25MB
  __half* Oc = VT + 64 * 9 * 2048;       // [B,T,64] f16 : 2MB

  k_ln_qkv<<<256, 256, 0, stream>>>(x, Wq, Wk, Wv, g1, bb1, Qh, Kh, VT);
  k_attn<<<dim3(64, 16), 256, 0, stream>>>(Qh, Kh, VT, Oc);
  k_proj_mlp<<<256, 256, 0, stream>>>(x, Oc, Wproj, bproj, W1, b1, W2, b2,
                                      g2, bb2, out);
}

// Round 11
// 74.684 us; speedup vs baseline: 1.1033x; 1.1033x over previous
//
#include <hip/hip_runtime.h>
#include <hip/hip_fp16.h>

#define DEV static __device__ __forceinline__

constexpr int NTOK = 8 * 2048;       // B*T
constexpr float LN_EPS = 1e-5f;

using half4  = __attribute__((ext_vector_type(4))) _Float16;
using half8  = __attribute__((ext_vector_type(8))) _Float16;
using f32x4  = __attribute__((ext_vector_type(4))) float;
using f32x16 = __attribute__((ext_vector_type(16))) float;

DEV __half2 bch2(unsigned u) { return __builtin_bit_cast(__half2, u); }
DEV unsigned bcu(__half2 h)  { return __builtin_bit_cast(unsigned, h); }

#define MFMA16(a, b, c)    __builtin_amdgcn_mfma_f32_16x16x16f16(a, b, c, 0, 0, 0)
#define MFMA32(a, b, c)    __builtin_amdgcn_mfma_f32_32x32x8f16(a, b, c, 0, 0, 0)
#define MFMA32X16(a, b, c) __builtin_amdgcn_mfma_f32_32x32x16_f16(a, b, c, 0, 0, 0)

DEV half4 pk4(float a, float b, float c, float d) {
  unsigned lo = __builtin_bit_cast(unsigned, __builtin_amdgcn_cvt_pkrtz(a, b));
  unsigned hi = __builtin_bit_cast(unsigned, __builtin_amdgcn_cvt_pkrtz(c, d));
  uint2 u = make_uint2(lo, hi);
  return __builtin_bit_cast(half4, u);
}
DEV half8 cat8(uint2 a, uint2 b) {
  uint4 u = make_uint4(a.x, a.y, b.x, b.y);
  return __builtin_bit_cast(half8, u);
}
DEV half8 cat8h(half4 a, half4 b) {
  return cat8(__builtin_bit_cast(uint2, a), __builtin_bit_cast(uint2, b));
}

// Schraudolph exp2: one v_fma_f32 + one v_cvt_i32_f32. Rel err [-2.2%,+3.0%];
// softmax denom uses the SAME approximated P (ones-row MFMA) -> common-mode.
DEV float schr(float x) {
  return __builtin_bit_cast(float, (int)__builtin_fmaf(x, 8388608.0f, 1064987473.0f));
}

// ------------------------------ K1: LN1 + QKV via MFMA transposed chain
__global__ __launch_bounds__(256) void k_ln_qkv(
    const float* __restrict__ x, const float* __restrict__ Wq,
    const float* __restrict__ Wk, const float* __restrict__ Wv,
    const float* __restrict__ g1, const float* __restrict__ b1g,
    __half* __restrict__ Qo, __half* __restrict__ Ko, __half* __restrict__ Vo)
{
  __shared__ __align__(16) __half WqF[4096];   // 8KB [mt4|kt4][lane][j]
  __shared__ __align__(16) __half WkF[4096];
  __shared__ __align__(16) __half WvF[4096];
  const int tid = threadIdx.x, lane = tid & 63, wid = tid >> 6;
  const int l15 = lane & 15, gg = lane >> 4;
  const float qs = 0.35355339059327373f * 1.4426950408889634f;  // hs^-0.5 * log2e
  for (int idx = tid; idx < 1024; idx += 256) {
    int mt = idx >> 8, kt = (idx >> 6) & 3, l = idx & 63;
    int row = l & 15, g = l >> 4;
    int off = (mt * 16 + row) * 64 + kt * 16 + g * 4;
    float4 a = *(const float4*)(Wq + off);
    float4 b = *(const float4*)(Wk + off);
    float4 c = *(const float4*)(Wv + off);
    half4 hq; hq[0] = (_Float16)(a.x*qs); hq[1] = (_Float16)(a.y*qs);
    hq[2] = (_Float16)(a.z*qs); hq[3] = (_Float16)(a.w*qs);
    half4 hk; hk[0] = (_Float16)b.x; hk[1] = (_Float16)b.y;
    hk[2] = (_Float16)b.z; hk[3] = (_Float16)b.w;
    half4 hv; hv[0] = (_Float16)c.x; hv[1] = (_Float16)c.y;
    hv[2] = (_Float16)c.z; hv[3] = (_Float16)c.w;
    *(half4*)&WqF[idx * 4] = hq;
    *(half4*)&WkF[idx * 4] = hk;
    *(half4*)&WvF[idx * 4] = hv;
  }
  __syncthreads();

  const int tok = (blockIdx.x * 4 + wid) * 16 + l15;
  const int b = tok >> 11, t = tok & 2047;
  float4 xv[4];
  float sum = 0.f, sq = 0.f;
  #pragma unroll
  for (int kt = 0; kt < 4; ++kt) {
    xv[kt] = *(const float4*)(x + tok * 64 + kt * 16 + gg * 4);
    sum += xv[kt].x + xv[kt].y + xv[kt].z + xv[kt].w;
    sq  += xv[kt].x*xv[kt].x + xv[kt].y*xv[kt].y
         + xv[kt].z*xv[kt].z + xv[kt].w*xv[kt].w;
  }
  sum += __shfl_xor(sum, 16); sum += __shfl_xor(sum, 32);
  sq  += __shfl_xor(sq, 16);  sq  += __shfl_xor(sq, 32);
  float mu = sum * (1.0f / 64.0f);
  float var = sq * (1.0f / 64.0f) - mu * mu;
  float rs = rsqrtf(var + LN_EPS);
  half4 hb[4];
  #pragma unroll
  for (int kt = 0; kt < 4; ++kt) {
    float4 gv = *(const float4*)(g1 + kt * 16 + gg * 4);
    float4 bv = *(const float4*)(b1g + kt * 16 + gg * 4);
    hb[kt][0] = (_Float16)((xv[kt].x - mu) * rs * gv.x + bv.x);
    hb[kt][1] = (_Float16)((xv[kt].y - mu) * rs * gv.y + bv.y);
    hb[kt][2] = (_Float16)((xv[kt].z - mu) * rs * gv.z + bv.z);
    hb[kt][3] = (_Float16)((xv[kt].w - mu) * rs * gv.w + bv.w);
  }
  #pragma unroll
  for (int mt = 0; mt < 4; ++mt) {
    f32x4 oq = {}, ok = {}, ov = {};
    #pragma unroll
    for (int kt = 0; kt < 4; ++kt) {
      half4 q_a = *(const half4*)&WqF[((mt * 4 + kt) * 64 + lane) * 4];
      half4 k_a = *(const half4*)&WkF[((mt * 4 + kt) * 64 + lane) * 4];
      half4 v_a = *(const half4*)&WvF[((mt * 4 + kt) * 64 + lane) * 4];
      oq = MFMA16(q_a, hb[kt], oq);
      ok = MFMA16(k_a, hb[kt], ok);
      ov = MFMA16(v_a, hb[kt], ov);
    }
    const int sg = mt * 16 + gg * 4;         // global output feature (h*8+s)
    const int h = sg >> 3, s = sg & 7;
    const long base = ((long)(b * 8 + h) * 2048 + t) * 8 + s;
    *(half4*)(Qo + base) = pk4(oq[0], oq[1], oq[2], oq[3]);
    *(half4*)(Ko + base) = pk4(ok[0], ok[1], ok[2], ok[3]);
    *(half4*)(Vo + base) = pk4(ov[0], ov[1], ov[2], ov[3]);
  }
}

// ---------------------------------------------------------------- K2: MFMA attention
// R8 structure + 64 q per wave. grid (64 bh, 8 q-blocks of 256), 4 waves,
// wave owns 64 q (2 tiles of 32: qf0/qf1). Every K-load and V^T-load is
// shared by both tiles (2 S-chains give intra-wave ILP). S^T = K·Q^T via
// 32x32x8 (K=8=hs); PV via 32x32x16: S C-regs ARE the PV B-frag. V^T in LDS
// stride 4128B; row 8 = ones -> denom = O^T row 8 (reg 4, hi=0 lanes);
// rows>8 clamp to ones row (pollutes only unread C rows). K streamed from
// global (L2) with 2-deep register double-buffer. Schraudolph softmax.
__global__ __launch_bounds__(256, 4) void k_attn(
    const __half* __restrict__ Qg, const __half* __restrict__ Kg,
    const __half* __restrict__ Vg, __half* __restrict__ Og)
{
  __shared__ __align__(16) char VTs[9 * 4128];   // V^T rows 0..7 + ones row
  const int tid = threadIdx.x, lane = tid & 63, wid = tid >> 6;
  const int bh = blockIdx.x;
  const int base = bh << 14;                  // *2048*8 elements
  // ---- stage V^T rows 0..7 (stride 4128), row 8 = ones
  const uint4* Vu = (const uint4*)(Vg + base);
  for (int i = tid; i < 1024; i += 256) {
    uint4 a = Vu[2 * i], bq = Vu[2 * i + 1];
    const unsigned short* pa = (const unsigned short*)&a;
    const unsigned short* pb = (const unsigned short*)&bq;
    #pragma unroll
    for (int d = 0; d < 8; ++d) {
      unsigned val = (unsigned)pa[d] | ((unsigned)pb[d] << 16);
      *(unsigned*)(VTs + d * 4128 + i * 4) = val;
    }
    *(unsigned*)(VTs + 8 * 4128 + i * 4) = 0x3C003C00u;  // half 1.0 pair
  }
  __syncthreads();

  const int b = bh >> 3, hh = bh & 7;
  const int l31 = lane & 31, hi = lane >> 5;
  const int q0 = blockIdx.y * 256 + wid * 64;
  // Q^T B-frags for two tiles (col=q=l31, k=hi*4+j)
  half4 qf0 = *(const half4*)((const char*)(Qg + base) + (q0 + l31) * 16 + hi * 8);
  half4 qf1 = *(const half4*)((const char*)(Qg + base) + (q0 + 32 + l31) * 16 + hi * 8);
  // K A-frag stream: row=key=l31, k=hi*4+j
  const char* kp = (const char*)(Kg + base) + l31 * 16 + hi * 8;
  // V^T A-frag base: row=d=l31 (clamp >=8 -> ones row), k-halves at hi*8 bytes
  const int deff = (l31 <= 8) ? l31 : 8;
  const char* vb = VTs + deff * 4128 + hi * 8;

  const f32x16 z = {};
  f32x16 o0 = {}, o1 = {};
  half4 kA[8], kB[8];
  #pragma unroll
  for (int u = 0; u < 8; ++u) kA[u] = *(const half4*)(kp + u * 512);

  // per 32-key body (byte IMM = c*64 into each V^T row), both q-tiles share
  // the K fragment and the 4 V^T uint2 loads.
  #define ATTN_BODY(KF, VB, IMM)                                               \
    {                                                                          \
      f32x16 s0 = MFMA32(KF, qf0, z);                                          \
      f32x16 s1 = MFMA32(KF, qf1, z);                                          \
      uint2 vl0 = *(const uint2*)((VB) + (IMM));                               \
      uint2 vh0 = *(const uint2*)((VB) + (IMM) + 16);                          \
      uint2 vl1 = *(const uint2*)((VB) + (IMM) + 32);                          \
      uint2 vh1 = *(const uint2*)((VB) + (IMM) + 48);                          \
      half4 pa0 = pk4(schr(s0[0]),  schr(s0[1]),  schr(s0[2]),  schr(s0[3]));  \
      half4 pa1 = pk4(schr(s0[4]),  schr(s0[5]),  schr(s0[6]),  schr(s0[7]));  \
      o0 = MFMA32X16(cat8(vl0, vh0), cat8h(pa0, pa1), o0);                     \
      half4 pb0 = pk4(schr(s1[0]),  schr(s1[1]),  schr(s1[2]),  schr(s1[3]));  \
      half4 pb1 = pk4(schr(s1[4]),  schr(s1[5]),  schr(s1[6]),  schr(s1[7]));  \
      o1 = MFMA32X16(cat8(vl0, vh0), cat8h(pb0, pb1), o1);                     \
      half4 pa2 = pk4(schr(s0[8]),  schr(s0[9]),  schr(s0[10]), schr(s0[11])); \
      half4 pa3 = pk4(schr(s0[12]), schr(s0[13]), schr(s0[14]), schr(s0[15])); \
      o0 = MFMA32X16(cat8(vl1, vh1), cat8h(pa2, pa3), o0);                     \
      half4 pb2 = pk4(schr(s1[8]),  schr(s1[9]),  schr(s1[10]), schr(s1[11])); \
      half4 pb3 = pk4(schr(s1[12]), schr(s1[13]), schr(s1[14]), schr(s1[15])); \
      o1 = MFMA32X16(cat8(vl1, vh1), cat8h(pb2, pb3), o1);                     \
    }

  #pragma unroll 1
  for (int gp = 0; gp < 4; ++gp) {
    const char* vbg = vb + gp * 1024;
    const char* kpe = kp + gp * 8192;
    #pragma unroll
    for (int u = 0; u < 8; ++u) kB[u] = *(const half4*)(kpe + 4096 + u * 512);
    #pragma unroll
    for (int u = 0; u < 8; ++u) ATTN_BODY(kA[u], vbg, u * 64);
    if (gp < 3) {
      #pragma unroll
      for (int u = 0; u < 8; ++u) kA[u] = *(const half4*)(kpe + 8192 + u * 512);
    }
    #pragma unroll
    for (int u = 0; u < 8; ++u) ATTN_BODY(kB[u], vbg, 512 + u * 64);
  }
  #undef ATTN_BODY

  // ---- epilogue: l = O^T row 8 (reg 4, hi=0 lanes); out rows r+4*hi
  {
    float l0 = __shfl(o0[4], l31);
    float inv = 1.0f / l0;
    half4 r;
    r[0] = (_Float16)(o0[0] * inv); r[1] = (_Float16)(o0[1] * inv);
    r[2] = (_Float16)(o0[2] * inv); r[3] = (_Float16)(o0[3] * inv);
    *(half4*)(Og + ((b * 2048 + q0 + l31) * 64) + hh * 8 + hi * 4) = r;
  }
  {
    float l1 = __shfl(o1[4], l31);
    float inv = 1.0f / l1;
    half4 r;
    r[0] = (_Float16)(o1[0] * inv); r[1] = (_Float16)(o1[1] * inv);
    r[2] = (_Float16)(o1[2] * inv); r[3] = (_Float16)(o1[3] * inv);
    *(half4*)(Og + ((b * 2048 + q0 + 32 + l31) * 64) + hh * 8 + hi * 4) = r;
  }
}

// ------------------------- K3: MFMA proj + res + LN2 + MLP + res (transposed chain)
// 64 blocks; weights staged ONCE per block, then 4 token-tile iterations per
// wave (weight L2 traffic 34MB -> 8.5MB).
__global__ __launch_bounds__(256) void k_proj_mlp(
    const float* __restrict__ x, const __half* __restrict__ Og,
    const float* __restrict__ Wproj, const float* __restrict__ bproj,
    const float* __restrict__ W1, const float* __restrict__ b1,
    const float* __restrict__ W2, const float* __restrict__ b2,
    const float* __restrict__ g2, const float* __restrict__ bb2,
    float* __restrict__ out)
{
  __shared__ __align__(16) __half WpF[4096];    // 8KB  [mt4|kt4][lane][j]
  __shared__ __align__(16) __half W1F[16384];   // 32KB [mt16|kt4][lane][j]
  __shared__ __align__(16) __half W2F[16384];   // 32KB [mt4|kt16][lane][j]
  __shared__ __align__(16) float biasLDS[512];  // bproj@0 g2@64 bb2@128 b2@192 b1@256
  const int tid = threadIdx.x, lane = tid & 63, wid = tid >> 6;
  const int l15 = lane & 15, gg = lane >> 4;

  for (int idx = tid; idx < 1024; idx += 256) {
    int mt = idx >> 8, kt = (idx >> 6) & 3, l = idx & 63;
    int row = l & 15, g = l >> 4;
    float4 w = *(const float4*)(Wproj + (mt * 16 + row) * 64 + kt * 16 + g * 4);
    half4 h; h[0] = (_Float16)w.x; h[1] = (_Float16)w.y;
    h[2] = (_Float16)w.z; h[3] = (_Float16)w.w;
    *(half4*)&WpF[idx * 4] = h;
  }
  for (int idx = tid; idx < 4096; idx += 256) {
    int mt2 = idx >> 8, kt = (idx >> 6) & 3, l = idx & 63;
    int row = l & 15, g = l >> 4;
    float4 w = *(const float4*)(W1 + (mt2 * 16 + row) * 64 + kt * 16 + g * 4);
    half4 h; h[0] = (_Float16)w.x; h[1] = (_Float16)w.y;
    h[2] = (_Float16)w.z; h[3] = (_Float16)w.w;
    *(half4*)&W1F[idx * 4] = h;
  }
  for (int idx = tid; idx < 4096; idx += 256) {
    int mt = idx >> 10, kt2 = (idx >> 6) & 15, l = idx & 63;
    int row = l & 15, g = l >> 4;
    float4 w = *(const float4*)(W2 + (mt * 16 + row) * 256 + kt2 * 16 + g * 4);
    half4 h; h[0] = (_Float16)w.x; h[1] = (_Float16)w.y;
    h[2] = (_Float16)w.z; h[3] = (_Float16)w.w;
    *(half4*)&W2F[idx * 4] = h;
  }
  for (int idx = tid; idx < 512; idx += 256) {
    float v;
    if      (idx <  64) v = bproj[idx];
    else if (idx < 128) v = g2[idx - 64];
    else if (idx < 192) v = bb2[idx - 128];
    else if (idx < 256) v = b2[idx - 192];
    else                v = b1[idx - 256];
    biasLDS[idx] = v;
  }
  __syncthreads();

  for (int it = 0; it < 4; ++it) {
    const int tile = blockIdx.x * 4 + wid + it * 256;
    const int tok = tile * 16 + l15;

    const __half* orow = Og + tok * 64;
    half4 ob[4];
    #pragma unroll
    for (int kt = 0; kt < 4; ++kt)
      ob[kt] = __builtin_bit_cast(half4, *(const uint2*)(orow + kt * 16 + gg * 4));

    f32x4 acc[4];
    #pragma unroll
    for (int mt = 0; mt < 4; ++mt) {
      float4 xv = *(const float4*)(x + tok * 64 + mt * 16 + gg * 4);
      float4 bp = *(const float4*)&biasLDS[mt * 16 + gg * 4];
      acc[mt] = (f32x4){xv.x + bp.x, xv.y + bp.y, xv.z + bp.z, xv.w + bp.w};
      #pragma unroll
      for (int kt = 0; kt < 4; ++kt) {
        half4 wa = *(const half4*)&WpF[((mt * 4 + kt) * 64 + lane) * 4];
        acc[mt] = MFMA16(wa, ob[kt], acc[mt]);
      }
    }
    float sum = 0.f, sq = 0.f;
    #pragma unroll
    for (int mt = 0; mt < 4; ++mt) {
      #pragma unroll
      for (int r = 0; r < 4; ++r) { float v = acc[mt][r]; sum += v; sq += v * v; }
    }
    sum += __shfl_xor(sum, 16); sum += __shfl_xor(sum, 32);
    sq  += __shfl_xor(sq, 16);  sq  += __shfl_xor(sq, 32);
    float mu = sum * (1.0f / 64.0f);
    float var = sq * (1.0f / 64.0f) - mu * mu;
    float rs = rsqrtf(var + LN_EPS);
    half4 hb[4];
    #pragma unroll
    for (int mt = 0; mt < 4; ++mt) {
      float4 gv = *(const float4*)&biasLDS[64 + mt * 16 + gg * 4];
      float4 bv = *(const float4*)&biasLDS[128 + mt * 16 + gg * 4];
      hb[mt][0] = (_Float16)((acc[mt][0] - mu) * rs * gv.x + bv.x);
      hb[mt][1] = (_Float16)((acc[mt][1] - mu) * rs * gv.y + bv.y);
      hb[mt][2] = (_Float16)((acc[mt][2] - mu) * rs * gv.z + bv.z);
      hb[mt][3] = (_Float16)((acc[mt][3] - mu) * rs * gv.w + bv.w);
    }
    half4 pf[16];
    #pragma unroll
    for (int mt2 = 0; mt2 < 16; ++mt2) {
      float4 b1v = *(const float4*)&biasLDS[256 + mt2 * 16 + gg * 4];
      f32x4 f = (f32x4){b1v.x, b1v.y, b1v.z, b1v.w};
      #pragma unroll
      for (int kt = 0; kt < 4; ++kt) {
        half4 wa = *(const half4*)&W1F[((mt2 * 4 + kt) * 64 + lane) * 4];
        f = MFMA16(wa, hb[kt], f);
      }
      pf[mt2][0] = (_Float16)fmaxf(f[0], 0.f);
      pf[mt2][1] = (_Float16)fmaxf(f[1], 0.f);
      pf[mt2][2] = (_Float16)fmaxf(f[2], 0.f);
      pf[mt2][3] = (_Float16)fmaxf(f[3], 0.f);
    }
    #pragma unroll
    for (int mt = 0; mt < 4; ++mt) {
      float4 b2v = *(const float4*)&biasLDS[192 + mt * 16 + gg * 4];
      f32x4 o = (f32x4){acc[mt][0] + b2v.x, acc[mt][1] + b2v.y,
                        acc[mt][2] + b2v.z, acc[mt][3] + b2v.w};
      #pragma unroll
      for (int kt2 = 0; kt2 < 16; ++kt2) {
        half4 wa = *(const half4*)&W2F[((mt * 16 + kt2) * 64 + lane) * 4];
        o = MFMA16(wa, pf[kt2], o);
      }
      *(float4*)(out + tok * 64 + mt * 16 + gg * 4) =
          make_float4(o[0], o[1], o[2], o[3]);
    }
  }
}

// ---------------------------------------------------------------- launch
extern "C" void kernel_launch(void* const* d_in, const int* in_sizes, int n_in,
                              void* d_out, int out_size, void* d_ws, size_t ws_size,
                              hipStream_t stream) {
  const float* x     = (const float*)d_in[0];
  const float* Wq    = (const float*)d_in[1];
  const float* Wk    = (const float*)d_in[2];
  const float* Wv    = (const float*)d_in[3];
  const float* Wproj = (const float*)d_in[4];
  const float* bproj = (const float*)d_in[5];
  const float* W1    = (const float*)d_in[6];
  const float* b1    = (const float*)d_in[7];
  const float* W2    = (const float*)d_in[8];
  const float* b2    = (const float*)d_in[9];
  const float* g1    = (const float*)d_in[10];
  const float* bb1   = (const float*)d_in[11];
  const float* g2    = (const float*)d_in[12];
  const float* bb2   = (const float*)d_in[13];
  float* out = (float*)d_out;

  __half* Qh = (__half*)d_ws;            // [64][2048][8] f16 : 2MB
  __half* Kh = Qh + 1048576;             // 2MB
  __half* Vh = Kh + 1048576;             // 2MB
  __half* Oc = Vh + 1048576;             // [B,T,64] f16 : 2MB

  k_ln_qkv<<<256, 256, 0, stream>>>(x, Wq, Wk, Wv, g1, bb1, Qh, Kh, Vh);
  k_attn<<<dim3(64, 8), 256, 0, stream>>>(Qh, Kh, Vh, Oc);
  k_proj_mlp<<<64, 256, 0, stream>>>(x, Oc, Wproj, bproj, W1, b1, W2, b2,
                                     g2, bb2, out);
}

// Round 12
// 50.687 us; speedup vs baseline: 1.6257x; 1.4734x over previous
//
#include <hip/hip_runtime.h>
#include <hip/hip_fp16.h>

#define DEV static __device__ __forceinline__

constexpr int NTOK = 8 * 2048;       // B*T
constexpr float LN_EPS = 1e-5f;

using half4  = __attribute__((ext_vector_type(4))) _Float16;
using half8  = __attribute__((ext_vector_type(8))) _Float16;
using f32x4  = __attribute__((ext_vector_type(4))) float;
using f32x16 = __attribute__((ext_vector_type(16))) float;

DEV __half2 bch2(unsigned u) { return __builtin_bit_cast(__half2, u); }
DEV unsigned bcu(__half2 h)  { return __builtin_bit_cast(unsigned, h); }

#define MFMA16(a, b, c)    __builtin_amdgcn_mfma_f32_16x16x16f16(a, b, c, 0, 0, 0)
#define MFMA32(a, b, c)    __builtin_amdgcn_mfma_f32_32x32x8f16(a, b, c, 0, 0, 0)
#define MFMA32X16(a, b, c) __builtin_amdgcn_mfma_f32_32x32x16_f16(a, b, c, 0, 0, 0)

DEV half4 pk4(float a, float b, float c, float d) {
  unsigned lo = __builtin_bit_cast(unsigned, __builtin_amdgcn_cvt_pkrtz(a, b));
  unsigned hi = __builtin_bit_cast(unsigned, __builtin_amdgcn_cvt_pkrtz(c, d));
  uint2 u = make_uint2(lo, hi);
  return __builtin_bit_cast(half4, u);
}
DEV half8 cat8(uint2 a, uint2 b) {
  uint4 u = make_uint4(a.x, a.y, b.x, b.y);
  return __builtin_bit_cast(half8, u);
}
DEV half8 cat8h(half4 a, half4 b) {
  return cat8(__builtin_bit_cast(uint2, a), __builtin_bit_cast(uint2, b));
}

// Schraudolph exp2: one v_fma_f32 + one v_cvt_i32_f32. Rel err [-2.2%,+3.0%];
// softmax denom uses the SAME approximated P (ones-row MFMA) -> common-mode.
DEV float schr(float x) {
  return __builtin_bit_cast(float, (int)__builtin_fmaf(x, 8388608.0f, 1064987473.0f));
}

// ------------------------------ K1: LN1 + QKV via MFMA transposed chain
__global__ __launch_bounds__(256) void k_ln_qkv(
    const float* __restrict__ x, const float* __restrict__ Wq,
    const float* __restrict__ Wk, const float* __restrict__ Wv,
    const float* __restrict__ g1, const float* __restrict__ b1g,
    __half* __restrict__ Qo, __half* __restrict__ Ko, __half* __restrict__ Vo)
{
  __shared__ __align__(16) __half WqF[4096];   // 8KB [mt4|kt4][lane][j]
  __shared__ __align__(16) __half WkF[4096];
  __shared__ __align__(16) __half WvF[4096];
  const int tid = threadIdx.x, lane = tid & 63, wid = tid >> 6;
  const int l15 = lane & 15, gg = lane >> 4;
  const float qs = 0.35355339059327373f * 1.4426950408889634f;  // hs^-0.5 * log2e
  for (int idx = tid; idx < 1024; idx += 256) {
    int mt = idx >> 8, kt = (idx >> 6) & 3, l = idx & 63;
    int row = l & 15, g = l >> 4;
    int off = (mt * 16 + row) * 64 + kt * 16 + g * 4;
    float4 a = *(const float4*)(Wq + off);
    float4 b = *(const float4*)(Wk + off);
    float4 c = *(const float4*)(Wv + off);
    half4 hq; hq[0] = (_Float16)(a.x*qs); hq[1] = (_Float16)(a.y*qs);
    hq[2] = (_Float16)(a.z*qs); hq[3] = (_Float16)(a.w*qs);
    half4 hk; hk[0] = (_Float16)b.x; hk[1] = (_Float16)b.y;
    hk[2] = (_Float16)b.z; hk[3] = (_Float16)b.w;
    half4 hv; hv[0] = (_Float16)c.x; hv[1] = (_Float16)c.y;
    hv[2] = (_Float16)c.z; hv[3] = (_Float16)c.w;
    *(half4*)&WqF[idx * 4] = hq;
    *(half4*)&WkF[idx * 4] = hk;
    *(half4*)&WvF[idx * 4] = hv;
  }
  __syncthreads();

  const int tok = (blockIdx.x * 4 + wid) * 16 + l15;
  const int b = tok >> 11, t = tok & 2047;
  float4 xv[4];
  float sum = 0.f, sq = 0.f;
  #pragma unroll
  for (int kt = 0; kt < 4; ++kt) {
    xv[kt] = *(const float4*)(x + tok * 64 + kt * 16 + gg * 4);
    sum += xv[kt].x + xv[kt].y + xv[kt].z + xv[kt].w;
    sq  += xv[kt].x*xv[kt].x + xv[kt].y*xv[kt].y
         + xv[kt].z*xv[kt].z + xv[kt].w*xv[kt].w;
  }
  sum += __shfl_xor(sum, 16); sum += __shfl_xor(sum, 32);
  sq  += __shfl_xor(sq, 16);  sq  += __shfl_xor(sq, 32);
  float mu = sum * (1.0f / 64.0f);
  float var = sq * (1.0f / 64.0f) - mu * mu;
  float rs = rsqrtf(var + LN_EPS);
  half4 hb[4];
  #pragma unroll
  for (int kt = 0; kt < 4; ++kt) {
    float4 gv = *(const float4*)(g1 + kt * 16 + gg * 4);
    float4 bv = *(const float4*)(b1g + kt * 16 + gg * 4);
    hb[kt][0] = (_Float16)((xv[kt].x - mu) * rs * gv.x + bv.x);
    hb[kt][1] = (_Float16)((xv[kt].y - mu) * rs * gv.y + bv.y);
    hb[kt][2] = (_Float16)((xv[kt].z - mu) * rs * gv.z + bv.z);
    hb[kt][3] = (_Float16)((xv[kt].w - mu) * rs * gv.w + bv.w);
  }
  #pragma unroll
  for (int mt = 0; mt < 4; ++mt) {
    f32x4 oq = {}, ok = {}, ov = {};
    #pragma unroll
    for (int kt = 0; kt < 4; ++kt) {
      half4 q_a = *(const half4*)&WqF[((mt * 4 + kt) * 64 + lane) * 4];
      half4 k_a = *(const half4*)&WkF[((mt * 4 + kt) * 64 + lane) * 4];
      half4 v_a = *(const half4*)&WvF[((mt * 4 + kt) * 64 + lane) * 4];
      oq = MFMA16(q_a, hb[kt], oq);
      ok = MFMA16(k_a, hb[kt], ok);
      ov = MFMA16(v_a, hb[kt], ov);
    }
    const int sg = mt * 16 + gg * 4;         // global output feature (h*8+s)
    const int h = sg >> 3, s = sg & 7;
    const long base = ((long)(b * 8 + h) * 2048 + t) * 8 + s;
    *(half4*)(Qo + base) = pk4(oq[0], oq[1], oq[2], oq[3]);
    *(half4*)(Ko + base) = pk4(ok[0], ok[1], ok[2], ok[3]);
    *(half4*)(Vo + base) = pk4(ov[0], ov[1], ov[2], ov[3]);
  }
}

// ---------------------------------------------------------------- K2: MFMA attention
// grid (64 bh, 8 q-blocks of 256), 4 waves, wave owns 64 q (2 tiles of 32:
// qf0/qf1). Every K-load and V^T-load shared by both tiles (2 S-chains give
// intra-wave ILP). S^T = K·Q^T via 32x32x8 (K=8=hs); PV via 32x32x16: S
// C-regs ARE the PV B-frag. V^T in LDS stride 4128B; row 8 = ones -> denom =
// O^T row 8 (reg 4); rows>8 clamp to ones row. K streamed from global (L2)
// with 2-deep register double-buffer. Schraudolph softmax.
__global__ __launch_bounds__(256, 4) void k_attn(
    const __half* __restrict__ Qg, const __half* __restrict__ Kg,
    const __half* __restrict__ Vg, __half* __restrict__ Og)
{
  __shared__ __align__(16) char VTs[9 * 4128];   // V^T rows 0..7 + ones row
  const int tid = threadIdx.x, lane = tid & 63, wid = tid >> 6;
  const int bh = blockIdx.x;
  const int base = bh << 14;                  // *2048*8 elements
  // ---- stage V^T rows 0..7 (stride 4128), row 8 = ones
  const uint4* Vu = (const uint4*)(Vg + base);
  for (int i = tid; i < 1024; i += 256) {
    uint4 a = Vu[2 * i], bq = Vu[2 * i + 1];
    const unsigned short* pa = (const unsigned short*)&a;
    const unsigned short* pb = (const unsigned short*)&bq;
    #pragma unroll
    for (int d = 0; d < 8; ++d) {
      unsigned val = (unsigned)pa[d] | ((unsigned)pb[d] << 16);
      *(unsigned*)(VTs + d * 4128 + i * 4) = val;
    }
    *(unsigned*)(VTs + 8 * 4128 + i * 4) = 0x3C003C00u;  // half 1.0 pair
  }
  __syncthreads();

  const int b = bh >> 3, hh = bh & 7;
  const int l31 = lane & 31, hi = lane >> 5;
  const int q0 = blockIdx.y * 256 + wid * 64;
  // Q^T B-frags for two tiles (col=q=l31, k=hi*4+j)
  half4 qf0 = *(const half4*)((const char*)(Qg + base) + (q0 + l31) * 16 + hi * 8);
  half4 qf1 = *(const half4*)((const char*)(Qg + base) + (q0 + 32 + l31) * 16 + hi * 8);
  // K A-frag stream: row=key=l31, k=hi*4+j
  const char* kp = (const char*)(Kg + base) + l31 * 16 + hi * 8;
  // V^T A-frag base: row=d=l31 (clamp >=8 -> ones row), k-halves at hi*8 bytes
  const int deff = (l31 <= 8) ? l31 : 8;
  const char* vb = VTs + deff * 4128 + hi * 8;

  const f32x16 z = {};
  f32x16 o0 = {}, o1 = {};
  half4 kA[8], kB[8];
  #pragma unroll
  for (int u = 0; u < 8; ++u) kA[u] = *(const half4*)(kp + u * 512);

  // per 32-key body (byte IMM = c*64 into each V^T row), both q-tiles share
  // the K fragment and the 4 V^T uint2 loads.
  #define ATTN_BODY(KF, VB, IMM)                                               \
    {                                                                          \
      f32x16 s0 = MFMA32(KF, qf0, z);                                          \
      f32x16 s1 = MFMA32(KF, qf1, z);                                          \
      uint2 vl0 = *(const uint2*)((VB) + (IMM));                               \
      uint2 vh0 = *(const uint2*)((VB) + (IMM) + 16);                          \
      uint2 vl1 = *(const uint2*)((VB) + (IMM) + 32);                          \
      uint2 vh1 = *(const uint2*)((VB) + (IMM) + 48);                          \
      half4 pa0 = pk4(schr(s0[0]),  schr(s0[1]),  schr(s0[2]),  schr(s0[3]));  \
      half4 pa1 = pk4(schr(s0[4]),  schr(s0[5]),  schr(s0[6]),  schr(s0[7]));  \
      o0 = MFMA32X16(cat8(vl0, vh0), cat8h(pa0, pa1), o0);                     \
      half4 pb0 = pk4(schr(s1[0]),  schr(s1[1]),  schr(s1[2]),  schr(s1[3]));  \
      half4 pb1 = pk4(schr(s1[4]),  schr(s1[5]),  schr(s1[6]),  schr(s1[7]));  \
      o1 = MFMA32X16(cat8(vl0, vh0), cat8h(pb0, pb1), o1);                     \
      half4 pa2 = pk4(schr(s0[8]),  schr(s0[9]),  schr(s0[10]), schr(s0[11])); \
      half4 pa3 = pk4(schr(s0[12]), schr(s0[13]), schr(s0[14]), schr(s0[15])); \
      o0 = MFMA32X16(cat8(vl1, vh1), cat8h(pa2, pa3), o0);                     \
      half4 pb2 = pk4(schr(s1[8]),  schr(s1[9]),  schr(s1[10]), schr(s1[11])); \
      half4 pb3 = pk4(schr(s1[12]), schr(s1[13]), schr(s1[14]), schr(s1[15])); \
      o1 = MFMA32X16(cat8(vl1, vh1), cat8h(pb2, pb3), o1);                     \
    }

  #pragma unroll 1
  for (int gp = 0; gp < 4; ++gp) {
    const char* vbg = vb + gp * 1024;
    const char* kpe = kp + gp * 8192;
    #pragma unroll
    for (int u = 0; u < 8; ++u) kB[u] = *(const half4*)(kpe + 4096 + u * 512);
    #pragma unroll
    for (int u = 0; u < 8; ++u) ATTN_BODY(kA[u], vbg, u * 64);
    if (gp < 3) {
      #pragma unroll
      for (int u = 0; u < 8; ++u) kA[u] = *(const half4*)(kpe + 8192 + u * 512);
    }
    #pragma unroll
    for (int u = 0; u < 8; ++u) ATTN_BODY(kB[u], vbg, 512 + u * 64);
  }
  #undef ATTN_BODY

  // ---- epilogue: l = O^T row 8 (reg 4); out rows r+4*hi
  {
    float l0 = __shfl(o0[4], l31);
    float inv = 1.0f / l0;
    half4 r;
    r[0] = (_Float16)(o0[0] * inv); r[1] = (_Float16)(o0[1] * inv);
    r[2] = (_Float16)(o0[2] * inv); r[3] = (_Float16)(o0[3] * inv);
    *(half4*)(Og + ((b * 2048 + q0 + l31) * 64) + hh * 8 + hi * 4) = r;
  }
  {
    float l1 = __shfl(o1[4], l31);
    float inv = 1.0f / l1;
    half4 r;
    r[0] = (_Float16)(o1[0] * inv); r[1] = (_Float16)(o1[1] * inv);
    r[2] = (_Float16)(o1[2] * inv); r[3] = (_Float16)(o1[3] * inv);
    *(half4*)(Og + ((b * 2048 + q0 + 32 + l31) * 64) + hh * 8 + hi * 4) = r;
  }
}

// ------------------------- K3: MFMA proj + res + LN2 + MLP + res (transposed chain)
// 256 blocks, one 16-token tile per wave (proven R8 config: ~9us, 88 VGPR).
__global__ __launch_bounds__(256) void k_proj_mlp(
    const float* __restrict__ x, const __half* __restrict__ Og,
    const float* __restrict__ Wproj, const float* __restrict__ bproj,
    const float* __restrict__ W1, const float* __restrict__ b1,
    const float* __restrict__ W2, const float* __restrict__ b2,
    const float* __restrict__ g2, const float* __restrict__ bb2,
    float* __restrict__ out)
{
  __shared__ __align__(16) __half WpF[4096];    // 8KB  [mt4|kt4][lane][j]
  __shared__ __align__(16) __half W1F[16384];   // 32KB [mt16|kt4][lane][j]
  __shared__ __align__(16) __half W2F[16384];   // 32KB [mt4|kt16][lane][j]
  __shared__ __align__(16) float biasLDS[512];  // bproj@0 g2@64 bb2@128 b2@192 b1@256
  const int tid = threadIdx.x, lane = tid & 63, wid = tid >> 6;
  const int l15 = lane & 15, gg = lane >> 4;

  for (int idx = tid; idx < 1024; idx += 256) {
    int mt = idx >> 8, kt = (idx >> 6) & 3, l = idx & 63;
    int row = l & 15, g = l >> 4;
    float4 w = *(const float4*)(Wproj + (mt * 16 + row) * 64 + kt * 16 + g * 4);
    half4 h; h[0] = (_Float16)w.x; h[1] = (_Float16)w.y;
    h[2] = (_Float16)w.z; h[3] = (_Float16)w.w;
    *(half4*)&WpF[idx * 4] = h;
  }
  for (int idx = tid; idx < 4096; idx += 256) {
    int mt2 = idx >> 8, kt = (idx >> 6) & 3, l = idx & 63;
    int row = l & 15, g = l >> 4;
    float4 w = *(const float4*)(W1 + (mt2 * 16 + row) * 64 + kt * 16 + g * 4);
    half4 h; h[0] = (_Float16)w.x; h[1] = (_Float16)w.y;
    h[2] = (_Float16)w.z; h[3] = (_Float16)w.w;
    *(half4*)&W1F[idx * 4] = h;
  }
  for (int idx = tid; idx < 4096; idx += 256) {
    int mt = idx >> 10, kt2 = (idx >> 6) & 15, l = idx & 63;
    int row = l & 15, g = l >> 4;
    float4 w = *(const float4*)(W2 + (mt * 16 + row) * 256 + kt2 * 16 + g * 4);
    half4 h; h[0] = (_Float16)w.x; h[1] = (_Float16)w.y;
    h[2] = (_Float16)w.z; h[3] = (_Float16)w.w;
    *(half4*)&W2F[idx * 4] = h;
  }
  for (int idx = tid; idx < 512; idx += 256) {
    float v;
    if      (idx <  64) v = bproj[idx];
    else if (idx < 128) v = g2[idx - 64];
    else if (idx < 192) v = bb2[idx - 128];
    else if (idx < 256) v = b2[idx - 192];
    else                v = b1[idx - 256];
    biasLDS[idx] = v;
  }
  __syncthreads();

  const int tile = blockIdx.x * 4 + wid;
  const int tok = tile * 16 + l15;

  const __half* orow = Og + tok * 64;
  half4 ob[4];
  #pragma unroll
  for (int kt = 0; kt < 4; ++kt)
    ob[kt] = __builtin_bit_cast(half4, *(const uint2*)(orow + kt * 16 + gg * 4));

  f32x4 acc[4];
  #pragma unroll
  for (int mt = 0; mt < 4; ++mt) {
    float4 xv = *(const float4*)(x + tok * 64 + mt * 16 + gg * 4);
    float4 bp = *(const float4*)&biasLDS[mt * 16 + gg * 4];
    acc[mt] = (f32x4){xv.x + bp.x, xv.y + bp.y, xv.z + bp.z, xv.w + bp.w};
    #pragma unroll
    for (int kt = 0; kt < 4; ++kt) {
      half4 wa = *(const half4*)&WpF[((mt * 4 + kt) * 64 + lane) * 4];
      acc[mt] = MFMA16(wa, ob[kt], acc[mt]);
    }
  }
  float sum = 0.f, sq = 0.f;
  #pragma unroll
  for (int mt = 0; mt < 4; ++mt) {
    #pragma unroll
    for (int r = 0; r < 4; ++r) { float v = acc[mt][r]; sum += v; sq += v * v; }
  }
  sum += __shfl_xor(sum, 16); sum += __shfl_xor(sum, 32);
  sq  += __shfl_xor(sq, 16);  sq  += __shfl_xor(sq, 32);
  float mu = sum * (1.0f / 64.0f);
  float var = sq * (1.0f / 64.0f) - mu * mu;
  float rs = rsqrtf(var + LN_EPS);
  half4 hb[4];
  #pragma unroll
  for (int mt = 0; mt < 4; ++mt) {
    float4 gv = *(const float4*)&biasLDS[64 + mt * 16 + gg * 4];
    float4 bv = *(const float4*)&biasLDS[128 + mt * 16 + gg * 4];
    hb[mt][0] = (_Float16)((acc[mt][0] - mu) * rs * gv.x + bv.x);
    hb[mt][1] = (_Float16)((acc[mt][1] - mu) * rs * gv.y + bv.y);
    hb[mt][2] = (_Float16)((acc[mt][2] - mu) * rs * gv.z + bv.z);
    hb[mt][3] = (_Float16)((acc[mt][3] - mu) * rs * gv.w + bv.w);
  }
  half4 pf[16];
  #pragma unroll
  for (int mt2 = 0; mt2 < 16; ++mt2) {
    float4 b1v = *(const float4*)&biasLDS[256 + mt2 * 16 + gg * 4];
    f32x4 f = (f32x4){b1v.x, b1v.y, b1v.z, b1v.w};
    #pragma unroll
    for (int kt = 0; kt < 4; ++kt) {
      half4 wa = *(const half4*)&W1F[((mt2 * 4 + kt) * 64 + lane) * 4];
      f = MFMA16(wa, hb[kt], f);
    }
    pf[mt2][0] = (_Float16)fmaxf(f[0], 0.f);
    pf[mt2][1] = (_Float16)fmaxf(f[1], 0.f);
    pf[mt2][2] = (_Float16)fmaxf(f[2], 0.f);
    pf[mt2][3] = (_Float16)fmaxf(f[3], 0.f);
  }
  #pragma unroll
  for (int mt = 0; mt < 4; ++mt) {
    float4 b2v = *(const float4*)&biasLDS[192 + mt * 16 + gg * 4];
    f32x4 o = (f32x4){acc[mt][0] + b2v.x, acc[mt][1] + b2v.y,
                      acc[mt][2] + b2v.z, acc[mt][3] + b2v.w};
    #pragma unroll
    for (int kt2 = 0; kt2 < 16; ++kt2) {
      half4 wa = *(const half4*)&W2F[((mt * 16 + kt2) * 64 + lane) * 4];
      o = MFMA16(wa, pf[kt2], o);
    }
    *(float4*)(out + tok * 64 + mt * 16 + gg * 4) =
        make_float4(o[0], o[1], o[2], o[3]);
  }
}

// ---------------------------------------------------------------- launch
extern "C" void kernel_launch(void* const* d_in, const int* in_sizes, int n_in,
                              void* d_out, int out_size, void* d_ws, size_t ws_size,
                              hipStream_t stream) {
  const float* x     = (const float*)d_in[0];
  const float* Wq    = (const float*)d_in[1];
  const float* Wk    = (const float*)d_in[2];
  const float* Wv    = (const float*)d_in[3];
  const float* Wproj = (const float*)d_in[4];
  const float* bproj = (const float*)d_in[5];
  const float* W1    = (const float*)d_in[6];
  const float* b1    = (const float*)d_in[7];
  const float* W2    = (const float*)d_in[8];
  const float* b2    = (const float*)d_in[9];
  const float* g1    = (const float*)d_in[10];
  const float* bb1   = (const float*)d_in[11];
  const float* g2    = (const float*)d_in[12];
  const float* bb2   = (const float*)d_in[13];
  float* out = (float*)d_out;

  __half* Qh = (__half*)d_ws;            // [64][2048][8] f16 : 2MB
  __half* Kh = Qh + 1048576;             // 2MB
  __half* Vh = Kh + 1048576;             // 2MB
  __half* Oc = Vh + 1048576;             // [B,T,64] f16 : 2MB

  k_ln_qkv<<<256, 256, 0, stream>>>(x, Wq, Wk, Wv, g1, bb1, Qh, Kh, Vh);
  k_attn<<<dim3(64, 8), 256, 0, stream>>>(Qh, Kh, Vh, Oc);
  k_proj_mlp<<<256, 256, 0, stream>>>(x, Oc, Wproj, bproj, W1, b1, W2, b2,
                                      g2, bb2, out);
}

// Round 13
// 46.363 us; speedup vs baseline: 1.7773x; 1.0933x over previous
//
#include <hip/hip_runtime.h>
#include <hip/hip_fp16.h>

#define DEV static __device__ __forceinline__

constexpr int NTOK = 8 * 2048;       // B*T
constexpr float LN_EPS = 1e-5f;

using half4  = __attribute__((ext_vector_type(4))) _Float16;
using half8  = __attribute__((ext_vector_type(8))) _Float16;
using f32x4  = __attribute__((ext_vector_type(4))) float;
using f32x16 = __attribute__((ext_vector_type(16))) float;

DEV __half2 bch2(unsigned u) { return __builtin_bit_cast(__half2, u); }
DEV unsigned bcu(__half2 h)  { return __builtin_bit_cast(unsigned, h); }

#define MFMA16(a, b, c)    __builtin_amdgcn_mfma_f32_16x16x16f16(a, b, c, 0, 0, 0)
#define MFMA32(a, b, c)    __builtin_amdgcn_mfma_f32_32x32x8f16(a, b, c, 0, 0, 0)
#define MFMA32X16(a, b, c) __builtin_amdgcn_mfma_f32_32x32x16_f16(a, b, c, 0, 0, 0)

DEV half4 pk4(float a, float b, float c, float d) {
  unsigned lo = __builtin_bit_cast(unsigned, __builtin_amdgcn_cvt_pkrtz(a, b));
  unsigned hi = __builtin_bit_cast(unsigned, __builtin_amdgcn_cvt_pkrtz(c, d));
  uint2 u = make_uint2(lo, hi);
  return __builtin_bit_cast(half4, u);
}
DEV half8 cat8(uint2 a, uint2 b) {
  uint4 u = make_uint4(a.x, a.y, b.x, b.y);
  return __builtin_bit_cast(half8, u);
}
DEV half8 cat8h(half4 a, half4 b) {
  return cat8(__builtin_bit_cast(uint2, a), __builtin_bit_cast(uint2, b));
}
// Schraudolph exp2 with the fma FOLDED INTO THE MFMA: S-MFMA computes
// s = x*2^23 + 1064987473 (Q pre-scaled 2^11, K 2^12, C = magic), so the
// softmax is just (int)s reinterpreted as f32. One v_cvt_i32_f32 per score.
DEV float ib(float x) { return __builtin_bit_cast(float, (int)x); }

// ------------------------------ K1: LN1 + QKV via MFMA transposed chain
// Q scale folds hs^-0.5 * log2e * 2^11; K scaled 2^12 (Schraudolph-in-MFMA).
__global__ __launch_bounds__(256) void k_ln_qkv(
    const float* __restrict__ x, const float* __restrict__ Wq,
    const float* __restrict__ Wk, const float* __restrict__ Wv,
    const float* __restrict__ g1, const float* __restrict__ b1g,
    __half* __restrict__ Qo, __half* __restrict__ Ko, __half* __restrict__ Vo)
{
  __shared__ __align__(16) __half WqF[4096];   // 8KB [mt4|kt4][lane][j]
  __shared__ __align__(16) __half WkF[4096];
  __shared__ __align__(16) __half WvF[4096];
  const int tid = threadIdx.x, lane = tid & 63, wid = tid >> 6;
  const int l15 = lane & 15, gg = lane >> 4;
  const float qs = 0.35355339059327373f * 1.4426950408889634f * 2048.0f;
  const float ks = 4096.0f;
  for (int idx = tid; idx < 1024; idx += 256) {
    int mt = idx >> 8, kt = (idx >> 6) & 3, l = idx & 63;
    int row = l & 15, g = l >> 4;
    int off = (mt * 16 + row) * 64 + kt * 16 + g * 4;
    float4 a = *(const float4*)(Wq + off);
    float4 b = *(const float4*)(Wk + off);
    float4 c = *(const float4*)(Wv + off);
    half4 hq; hq[0] = (_Float16)(a.x*qs); hq[1] = (_Float16)(a.y*qs);
    hq[2] = (_Float16)(a.z*qs); hq[3] = (_Float16)(a.w*qs);
    half4 hk; hk[0] = (_Float16)(b.x*ks); hk[1] = (_Float16)(b.y*ks);
    hk[2] = (_Float16)(b.z*ks); hk[3] = (_Float16)(b.w*ks);
    half4 hv; hv[0] = (_Float16)c.x; hv[1] = (_Float16)c.y;
    hv[2] = (_Float16)c.z; hv[3] = (_Float16)c.w;
    *(half4*)&WqF[idx * 4] = hq;
    *(half4*)&WkF[idx * 4] = hk;
    *(half4*)&WvF[idx * 4] = hv;
  }
  __syncthreads();

  const int tok = (blockIdx.x * 4 + wid) * 16 + l15;
  const int b = tok >> 11, t = tok & 2047;
  float4 xv[4];
  float sum = 0.f, sq = 0.f;
  #pragma unroll
  for (int kt = 0; kt < 4; ++kt) {
    xv[kt] = *(const float4*)(x + tok * 64 + kt * 16 + gg * 4);
    sum += xv[kt].x + xv[kt].y + xv[kt].z + xv[kt].w;
    sq  += xv[kt].x*xv[kt].x + xv[kt].y*xv[kt].y
         + xv[kt].z*xv[kt].z + xv[kt].w*xv[kt].w;
  }
  sum += __shfl_xor(sum, 16); sum += __shfl_xor(sum, 32);
  sq  += __shfl_xor(sq, 16);  sq  += __shfl_xor(sq, 32);
  float mu = sum * (1.0f / 64.0f);
  float var = sq * (1.0f / 64.0f) - mu * mu;
  float rs = rsqrtf(var + LN_EPS);
  half4 hb[4];
  #pragma unroll
  for (int kt = 0; kt < 4; ++kt) {
    float4 gv = *(const float4*)(g1 + kt * 16 + gg * 4);
    float4 bv = *(const float4*)(b1g + kt * 16 + gg * 4);
    hb[kt][0] = (_Float16)((xv[kt].x - mu) * rs * gv.x + bv.x);
    hb[kt][1] = (_Float16)((xv[kt].y - mu) * rs * gv.y + bv.y);
    hb[kt][2] = (_Float16)((xv[kt].z - mu) * rs * gv.z + bv.z);
    hb[kt][3] = (_Float16)((xv[kt].w - mu) * rs * gv.w + bv.w);
  }
  #pragma unroll
  for (int mt = 0; mt < 4; ++mt) {
    f32x4 oq = {}, ok = {}, ov = {};
    #pragma unroll
    for (int kt = 0; kt < 4; ++kt) {
      half4 q_a = *(const half4*)&WqF[((mt * 4 + kt) * 64 + lane) * 4];
      half4 k_a = *(const half4*)&WkF[((mt * 4 + kt) * 64 + lane) * 4];
      half4 v_a = *(const half4*)&WvF[((mt * 4 + kt) * 64 + lane) * 4];
      oq = MFMA16(q_a, hb[kt], oq);
      ok = MFMA16(k_a, hb[kt], ok);
      ov = MFMA16(v_a, hb[kt], ov);
    }
    const int sg = mt * 16 + gg * 4;         // global output feature (h*8+s)
    const int h = sg >> 3, s = sg & 7;
    const long base = ((long)(b * 8 + h) * 2048 + t) * 8 + s;
    *(half4*)(Qo + base) = pk4(oq[0], oq[1], oq[2], oq[3]);
    *(half4*)(Ko + base) = pk4(ok[0], ok[1], ok[2], ok[3]);
    *(half4*)(Vo + base) = pk4(ov[0], ov[1], ov[2], ov[3]);
  }
}

// ---------------------------------------------------------------- K2: MFMA attention
// grid (64 bh, 8), 4 waves, wave owns 64 q (2 tiles of 32). S^T = K·Q^T via
// 32x32x8 with C = Schraudolph magic (s = x*2^23 + magic); softmax = one
// v_cvt_i32_f32 per score. PV via 32x32x16 (S C-regs ARE the PV B-frag).
// S-MFMAs software-pipelined one body ahead; 4 independent PV accumulators
// (per-tile lo/hi key-halves) kill accumulation stalls. V^T in LDS (stride
// 4128B); row 8 = ones -> denom = O row 8. K global-streamed, double-buffered.
__global__ __launch_bounds__(256, 2) void k_attn(
    const __half* __restrict__ Qg, const __half* __restrict__ Kg,
    const __half* __restrict__ Vg, __half* __restrict__ Og)
{
  __shared__ __align__(16) char VTs[9 * 4128];   // V^T rows 0..7 + ones row
  const int tid = threadIdx.x, lane = tid & 63, wid = tid >> 6;
  const int bh = blockIdx.x;
  const int base = bh << 14;                  // *2048*8 elements
  // ---- stage V^T rows 0..7 (stride 4128), row 8 = ones
  const uint4* Vu = (const uint4*)(Vg + base);
  for (int i = tid; i < 1024; i += 256) {
    uint4 a = Vu[2 * i], bq = Vu[2 * i + 1];
    const unsigned short* pa = (const unsigned short*)&a;
    const unsigned short* pb = (const unsigned short*)&bq;
    #pragma unroll
    for (int d = 0; d < 8; ++d) {
      unsigned val = (unsigned)pa[d] | ((unsigned)pb[d] << 16);
      *(unsigned*)(VTs + d * 4128 + i * 4) = val;
    }
    *(unsigned*)(VTs + 8 * 4128 + i * 4) = 0x3C003C00u;  // half 1.0 pair
  }
  __syncthreads();

  const int b = bh >> 3, hh = bh & 7;
  const int l31 = lane & 31, hi = lane >> 5;
  const int q0 = blockIdx.y * 256 + wid * 64;
  half4 qf0 = *(const half4*)((const char*)(Qg + base) + (q0 + l31) * 16 + hi * 8);
  half4 qf1 = *(const half4*)((const char*)(Qg + base) + (q0 + 32 + l31) * 16 + hi * 8);
  const char* kp = (const char*)(Kg + base) + l31 * 16 + hi * 8;
  const int deff = (l31 <= 8) ? l31 : 8;
  const char* vb = VTs + deff * 4128 + hi * 8;

  f32x16 cm;
  #pragma unroll
  for (int i = 0; i < 16; ++i) cm[i] = 1064987473.0f;   // Schraudolph magic

  f32x16 o0l = {}, o0h = {}, o1l = {}, o1h = {};
  half4 kA[8], kB[8];
  #pragma unroll
  for (int u = 0; u < 8; ++u) kA[u] = *(const half4*)(kp + u * 512);

  // PV of one 32-key body; S values already computed (pipelined).
  #define PVB(SC0, SC1, VB, IMM)                                               \
    {                                                                          \
      uint2 vl0 = *(const uint2*)((VB) + (IMM));                               \
      uint2 vh0 = *(const uint2*)((VB) + (IMM) + 16);                          \
      uint2 vl1 = *(const uint2*)((VB) + (IMM) + 32);                          \
      uint2 vh1 = *(const uint2*)((VB) + (IMM) + 48);                          \
      half4 pa0 = pk4(ib(SC0[0]),  ib(SC0[1]),  ib(SC0[2]),  ib(SC0[3]));      \
      half4 pa1 = pk4(ib(SC0[4]),  ib(SC0[5]),  ib(SC0[6]),  ib(SC0[7]));      \
      o0l = MFMA32X16(cat8(vl0, vh0), cat8h(pa0, pa1), o0l);                   \
      half4 pb0 = pk4(ib(SC1[0]),  ib(SC1[1]),  ib(SC1[2]),  ib(SC1[3]));      \
      half4 pb1 = pk4(ib(SC1[4]),  ib(SC1[5]),  ib(SC1[6]),  ib(SC1[7]));      \
      o1l = MFMA32X16(cat8(vl0, vh0), cat8h(pb0, pb1), o1l);                   \
      half4 pa2 = pk4(ib(SC0[8]),  ib(SC0[9]),  ib(SC0[10]), ib(SC0[11]));     \
      half4 pa3 = pk4(ib(SC0[12]), ib(SC0[13]), ib(SC0[14]), ib(SC0[15]));     \
      o0h = MFMA32X16(cat8(vl1, vh1), cat8h(pa2, pa3), o0h);                   \
      half4 pb2 = pk4(ib(SC1[8]),  ib(SC1[9]),  ib(SC1[10]), ib(SC1[11]));     \
      half4 pb3 = pk4(ib(SC1[12]), ib(SC1[13]), ib(SC1[14]), ib(SC1[15]));     \
      o1h = MFMA32X16(cat8(vl1, vh1), cat8h(pb2, pb3), o1h);                   \
    }

  f32x16 sc0 = MFMA32(kA[0], qf0, cm);
  f32x16 sc1 = MFMA32(kA[0], qf1, cm);

  #pragma unroll 1
  for (int gp = 0; gp < 4; ++gp) {
    const char* vbg = vb + gp * 1024;
    const char* kpe = kp + gp * 8192;
    #pragma unroll
    for (int u = 0; u < 8; ++u) kB[u] = *(const half4*)(kpe + 4096 + u * 512);
    #pragma unroll
    for (int u = 0; u < 8; ++u) {
      half4 kn = (u < 7) ? kA[u + 1] : kB[0];
      f32x16 sn0 = MFMA32(kn, qf0, cm);
      f32x16 sn1 = MFMA32(kn, qf1, cm);
      PVB(sc0, sc1, vbg, u * 64);
      sc0 = sn0; sc1 = sn1;
    }
    if (gp < 3) {
      #pragma unroll
      for (int u = 0; u < 8; ++u) kA[u] = *(const half4*)(kpe + 8192 + u * 512);
    }
    #pragma unroll
    for (int u = 0; u < 8; ++u) {
      half4 kn = (u < 7) ? kB[u + 1] : kA[0];   // gp==3: dummy (unused result)
      f32x16 sn0 = MFMA32(kn, qf0, cm);
      f32x16 sn1 = MFMA32(kn, qf1, cm);
      PVB(sc0, sc1, vbg, 512 + u * 64);
      sc0 = sn0; sc1 = sn1;
    }
  }
  #undef PVB

  // ---- epilogue: merge accum halves; l = O^T row 8 (reg 4); out rows r+4*hi
  {
    f32x16 o0 = o0l + o0h;
    float l0 = __shfl(o0[4], l31);
    float inv = 1.0f / l0;
    half4 r;
    r[0] = (_Float16)(o0[0] * inv); r[1] = (_Float16)(o0[1] * inv);
    r[2] = (_Float16)(o0[2] * inv); r[3] = (_Float16)(o0[3] * inv);
    *(half4*)(Og + ((b * 2048 + q0 + l31) * 64) + hh * 8 + hi * 4) = r;
  }
  {
    f32x16 o1 = o1l + o1h;
    float l1 = __shfl(o1[4], l31);
    float inv = 1.0f / l1;
    half4 r;
    r[0] = (_Float16)(o1[0] * inv); r[1] = (_Float16)(o1[1] * inv);
    r[2] = (_Float16)(o1[2] * inv); r[3] = (_Float16)(o1[3] * inv);
    *(half4*)(Og + ((b * 2048 + q0 + 32 + l31) * 64) + hh * 8 + hi * 4) = r;
  }
}

// ------------------------- K3: MFMA proj + res + LN2 + MLP + res (transposed chain)
// 256 blocks, one 16-token tile per wave (proven R8 config: ~9us, 88 VGPR).
__global__ __launch_bounds__(256) void k_proj_mlp(
    const float* __restrict__ x, const __half* __restrict__ Og,
    const float* __restrict__ Wproj, const float* __restrict__ bproj,
    const float* __restrict__ W1, const float* __restrict__ b1,
    const float* __restrict__ W2, const float* __restrict__ b2,
    const float* __restrict__ g2, const float* __restrict__ bb2,
    float* __restrict__ out)
{
  __shared__ __align__(16) __half WpF[4096];    // 8KB  [mt4|kt4][lane][j]
  __shared__ __align__(16) __half W1F[16384];   // 32KB [mt16|kt4][lane][j]
  __shared__ __align__(16) __half W2F[16384];   // 32KB [mt4|kt16][lane][j]
  __shared__ __align__(16) float biasLDS[512];  // bproj@0 g2@64 bb2@128 b2@192 b1@256
  const int tid = threadIdx.x, lane = tid & 63, wid = tid >> 6;
  const int l15 = lane & 15, gg = lane >> 4;

  for (int idx = tid; idx < 1024; idx += 256) {
    int mt = idx >> 8, kt = (idx >> 6) & 3, l = idx & 63;
    int row = l & 15, g = l >> 4;
    float4 w = *(const float4*)(Wproj + (mt * 16 + row) * 64 + kt * 16 + g * 4);
    half4 h; h[0] = (_Float16)w.x; h[1] = (_Float16)w.y;
    h[2] = (_Float16)w.z; h[3] = (_Float16)w.w;
    *(half4*)&WpF[idx * 4] = h;
  }
  for (int idx = tid; idx < 4096; idx += 256) {
    int mt2 = idx >> 8, kt = (idx >> 6) & 3, l = idx & 63;
    int row = l & 15, g = l >> 4;
    float4 w = *(const float4*)(W1 + (mt2 * 16 + row) * 64 + kt * 16 + g * 4);
    half4 h; h[0] = (_Float16)w.x; h[1] = (_Float16)w.y;
    h[2] = (_Float16)w.z; h[3] = (_Float16)w.w;
    *(half4*)&W1F[idx * 4] = h;
  }
  for (int idx = tid; idx < 4096; idx += 256) {
    int mt = idx >> 10, kt2 = (idx >> 6) & 15, l = idx & 63;
    int row = l & 15, g = l >> 4;
    float4 w = *(const float4*)(W2 + (mt * 16 + row) * 256 + kt2 * 16 + g * 4);
    half4 h; h[0] = (_Float16)w.x; h[1] = (_Float16)w.y;
    h[2] = (_Float16)w.z; h[3] = (_Float16)w.w;
    *(half4*)&W2F[idx * 4] = h;
  }
  for (int idx = tid; idx < 512; idx += 256) {
    float v;
    if      (idx <  64) v = bproj[idx];
    else if (idx < 128) v = g2[idx - 64];
    else if (idx < 192) v = bb2[idx - 128];
    else if (idx < 256) v = b2[idx - 192];
    else                v = b1[idx - 256];
    biasLDS[idx] = v;
  }
  __syncthreads();

  const int tile = blockIdx.x * 4 + wid;
  const int tok = tile * 16 + l15;

  const __half* orow = Og + tok * 64;
  half4 ob[4];
  #pragma unroll
  for (int kt = 0; kt < 4; ++kt)
    ob[kt] = __builtin_bit_cast(half4, *(const uint2*)(orow + kt * 16 + gg * 4));

  f32x4 acc[4];
  #pragma unroll
  for (int mt = 0; mt < 4; ++mt) {
    float4 xv = *(const float4*)(x + tok * 64 + mt * 16 + gg * 4);
    float4 bp = *(const float4*)&biasLDS[mt * 16 + gg * 4];
    acc[mt] = (f32x4){xv.x + bp.x, xv.y + bp.y, xv.z + bp.z, xv.w + bp.w};
    #pragma unroll
    for (int kt = 0; kt < 4; ++kt) {
      half4 wa = *(const half4*)&WpF[((mt * 4 + kt) * 64 + lane) * 4];
      acc[mt] = MFMA16(wa, ob[kt], acc[mt]);
    }
  }
  float sum = 0.f, sq = 0.f;
  #pragma unroll
  for (int mt = 0; mt < 4; ++mt) {
    #pragma unroll
    for (int r = 0; r < 4; ++r) { float v = acc[mt][r]; sum += v; sq += v * v; }
  }
  sum += __shfl_xor(sum, 16); sum += __shfl_xor(sum, 32);
  sq  += __shfl_xor(sq, 16);  sq  += __shfl_xor(sq, 32);
  float mu = sum * (1.0f / 64.0f);
  float var = sq * (1.0f / 64.0f) - mu * mu;
  float rs = rsqrtf(var + LN_EPS);
  half4 hb[4];
  #pragma unroll
  for (int mt = 0; mt < 4; ++mt) {
    float4 gv = *(const float4*)&biasLDS[64 + mt * 16 + gg * 4];
    float4 bv = *(const float4*)&biasLDS[128 + mt * 16 + gg * 4];
    hb[mt][0] = (_Float16)((acc[mt][0] - mu) * rs * gv.x + bv.x);
    hb[mt][1] = (_Float16)((acc[mt][1] - mu) * rs * gv.y + bv.y);
    hb[mt][2] = (_Float16)((acc[mt][2] - mu) * rs * gv.z + bv.z);
    hb[mt][3] = (_Float16)((acc[mt][3] - mu) * rs * gv.w + bv.w);
  }
  half4 pf[16];
  #pragma unroll
  for (int mt2 = 0; mt2 < 16; ++mt2) {
    float4 b1v = *(const float4*)&biasLDS[256 + mt2 * 16 + gg * 4];
    f32x4 f = (f32x4){b1v.x, b1v.y, b1v.z, b1v.w};
    #pragma unroll
    for (int kt = 0; kt < 4; ++kt) {
      half4 wa = *(const half4*)&W1F[((mt2 * 4 + kt) * 64 + lane) * 4];
      f = MFMA16(wa, hb[kt], f);
    }
    pf[mt2][0] = (_Float16)fmaxf(f[0], 0.f);
    pf[mt2][1] = (_Float16)fmaxf(f[1], 0.f);
    pf[mt2][2] = (_Float16)fmaxf(f[2], 0.f);
    pf[mt2][3] = (_Float16)fmaxf(f[3], 0.f);
  }
  #pragma unroll
  for (int mt = 0; mt < 4; ++mt) {
    float4 b2v = *(const float4*)&biasLDS[192 + mt * 16 + gg * 4];
    f32x4 o = (f32x4){acc[mt][0] + b2v.x, acc[mt][1] + b2v.y,
                      acc[mt][2] + b2v.z, acc[mt][3] + b2v.w};
    #pragma unroll
    for (int kt2 = 0; kt2 < 16; ++kt2) {
      half4 wa = *(const half4*)&W2F[((mt * 16 + kt2) * 64 + lane) * 4];
      o = MFMA16(wa, pf[kt2], o);
    }
    *(float4*)(out + tok * 64 + mt * 16 + gg * 4) =
        make_float4(o[0], o[1], o[2], o[3]);
  }
}

// ---------------------------------------------------------------- launch
extern "C" void kernel_launch(void* const* d_in, const int* in_sizes, int n_in,
                              void* d_out, int out_size, void* d_ws, size_t ws_size,
                              hipStream_t stream) {
  const float* x     = (const float*)d_in[0];
  const float* Wq    = (const float*)d_in[1];
  const float* Wk    = (const float*)d_in[2];
  const float* Wv    = (const float*)d_in[3];
  const float* Wproj = (const float*)d_in[4];
  const float* bproj = (const float*)d_in[5];
  const float* W1    = (const float*)d_in[6];
  const float* b1    = (const float*)d_in[7];
  const float* W2    = (const float*)d_in[8];
  const float* b2    = (const float*)d_in[9];
  const float* g1    = (const float*)d_in[10];
  const float* bb1   = (const float*)d_in[11];
  const float* g2    = (const float*)d_in[12];
  const float* bb2   = (const float*)d_in[13];
  float* out = (float*)d_out;

  __half* Qh = (__half*)d_ws;            // [64][2048][8] f16 : 2MB
  __half* Kh = Qh + 1048576;             // 2MB
  __half* Vh = Kh + 1048576;             // 2MB
  __half* Oc = Vh + 1048576;             // [B,T,64] f16 : 2MB

  k_ln_qkv<<<256, 256, 0, stream>>>(x, Wq, Wk, Wv, g1, bb1, Qh, Kh, Vh);
  k_attn<<<dim3(64, 8), 256, 0, stream>>>(Qh, Kh, Vh, Oc);
  k_proj_mlp<<<256, 256, 0, stream>>>(x, Oc, Wproj, bproj, W1, b1, W2, b2,
                                      g2, bb2, out);
}